// Round 3
// baseline (633.731 us; speedup 1.0000x reference)
//
#include <hip/hip_runtime.h>

typedef __attribute__((ext_vector_type(8))) short short8;
typedef __attribute__((ext_vector_type(16))) float f32x16;

// d_ws layout (ushort elements):
#define WS_GT   0        // 26*8 = 208 bf16
#define WS_CT   256      // 27*8 = 216 bf16
#define WS_W1T  512      // 256 cols * 13 slots * 8 bf16 = 26624 ushorts (52 KB)

__device__ __forceinline__ unsigned short f2bf(float f) {
    unsigned int u = __float_as_uint(f);
    u = (u + 0x7fffu + ((u >> 16) & 1u)) >> 16;   // RNE
    return (unsigned short)u;
}
__device__ __forceinline__ float bflo(unsigned int w) { return __uint_as_float(w << 16); }
__device__ __forceinline__ float bfhi(unsigned int w) { return __uint_as_float(w & 0xffff0000u); }

// W1 stored transposed [col][13 slots of 8]; 208 B col stride (odd multiple of
// 16 B -> ds_read_b128 conflict-free without swizzle). Slot s = kk*2+hi holds
// logical chunk per the half-wave split; slot 12 is pad.
__global__ __launch_bounds__(256) void prep_kernel(
    const float* __restrict__ gt, const float* __restrict__ ct,
    const float* __restrict__ W1, unsigned short* __restrict__ ws)
{
    int tid = blockIdx.x * 256 + threadIdx.x;
    if (tid < 208) ws[WS_GT + tid] = f2bf(gt[tid]);
    if (tid < 216) ws[WS_CT + tid] = f2bf(ct[tid]);
    if (tid < 24576) {
        int kl  = tid >> 8;     // logical k 0..95
        int col = tid & 255;    // hidden col 0..255
        int chunk = kl >> 3, j = kl & 7;
        int hi, kk;
        if (chunk < 5)        { hi = 0; kk = chunk; }      // guess letters -> half 0
        else if (chunk < 10)  { hi = 1; kk = chunk - 5; }  // constraint letters -> half 1
        else if (chunk == 10) { hi = 0; kk = 5; }          // presence mean -> half 0
        else                  { hi = 1; kk = 5; }          // absent mean  -> half 1
        int s = kk * 2 + hi;                                // physical k-slot 0..11
        ws[WS_W1T + col * 104 + s * 8 + j] = f2bf(W1[kl * 256 + col]);
    }
}

__global__ __launch_bounds__(256, 3) void wordle_kernel(
    const int* __restrict__ gidx, const int* __restrict__ cidx,
    const int* __restrict__ pidx, const int* __restrict__ plen,
    const int* __restrict__ aidx, const int* __restrict__ alen,
    const float* __restrict__ b1, const float* __restrict__ W2,
    const float* __restrict__ b2, const unsigned short* __restrict__ ws,
    float* __restrict__ out, int tilesPerBlock)
{
    __shared__ unsigned short w1t[26624];   // 52 KB

    // Stage W1T (linear coalesced copy; layout pre-applied in d_ws)
    {
        const uint4* src = (const uint4*)(ws + WS_W1T);
        uint4* dst = (uint4*)w1t;
        int tid = threadIdx.x;
        #pragma unroll
        for (int i = 0; i < 13; ++i) dst[tid + i * 256] = src[tid + i * 256];
    }
    __syncthreads();

    const int lane = threadIdx.x & 63;
    const int wv   = threadIdx.x >> 6;
    const int l31  = lane & 31;
    const int hi   = lane >> 5;
    const unsigned short* gt = ws + WS_GT;
    const unsigned short* ct = ws + WS_CT;
    const unsigned short* tb = hi ? ct : gt;
    const float b2v = b2[0];

    // Hoist epilogue weights into registers (8 col-tiles of 32)
    float w2r[8], b1r[8];
    #pragma unroll
    for (int nt = 0; nt < 8; ++nt) {
        w2r[nt] = W2[nt * 32 + l31];
        b1r[nt] = b1[nt * 32 + l31];
    }

    // Prefetched per-row indices for the CURRENT tile
    int ip0, ip1, ip2, ip3, ip4;
    int s0, s1, s2, s3, s4, s5, s6, s7, s8, s9;
    int lenv;

#define LOADIDX(T) do {                                                     \
        const int r_ = (blockIdx.x * tilesPerBlock + (T)) * 128 + wv * 32 + l31; \
        const int* ip_ = (hi ? cidx : gidx) + r_ * 5;                       \
        ip0 = ip_[0]; ip1 = ip_[1]; ip2 = ip_[2]; ip3 = ip_[3]; ip4 = ip_[4]; \
        const int* si_ = (hi ? aidx : pidx) + r_ * 10;                      \
        s0 = si_[0]; s1 = si_[1]; s2 = si_[2]; s3 = si_[3]; s4 = si_[4];    \
        s5 = si_[5]; s6 = si_[6]; s7 = si_[7]; s8 = si_[8]; s9 = si_[9];    \
        lenv = (hi ? alen : plen)[r_];                                      \
    } while (0)

    LOADIDX(0);

    for (int t = 0; t < tilesPerBlock; ++t) {
        const int tile = blockIdx.x * tilesPerBlock + t;

        // ---------- gather: issue all table loads for this tile ----------
        short8 a0 = *(const short8*)(tb + ip0 * 8);
        short8 a1 = *(const short8*)(tb + ip1 * 8);
        short8 a2 = *(const short8*)(tb + ip2 * 8);
        short8 a3 = *(const short8*)(tb + ip3 * 8);
        short8 a4 = *(const short8*)(tb + ip4 * 8);
        uint4 e0 = *(const uint4*)(gt + s0 * 8);
        uint4 e1 = *(const uint4*)(gt + s1 * 8);
        uint4 e2 = *(const uint4*)(gt + s2 * 8);
        uint4 e3 = *(const uint4*)(gt + s3 * 8);
        uint4 e4 = *(const uint4*)(gt + s4 * 8);
        uint4 e5 = *(const uint4*)(gt + s5 * 8);
        uint4 e6 = *(const uint4*)(gt + s6 * 8);
        uint4 e7 = *(const uint4*)(gt + s7 * 8);
        uint4 e8 = *(const uint4*)(gt + s8 * 8);
        uint4 e9 = *(const uint4*)(gt + s9 * 8);
        const int len = lenv;

        // ---------- prefetch next tile's indices (hides under MFMA) ----------
        if (t + 1 < tilesPerBlock) LOADIDX(t + 1);

        // ---------- masked mean -> a5 ----------
        short8 a5;
        {
            float m0=0.f,m1=0.f,m2=0.f,m3=0.f,m4=0.f,m5=0.f,m6=0.f,m7=0.f;
            uint4 ev[10] = {e0,e1,e2,e3,e4,e5,e6,e7,e8,e9};
            #pragma unroll
            for (int k = 0; k < 10; ++k) {
                float w = (k < len) ? 1.f : 0.f;
                m0 += w * bflo(ev[k].x); m1 += w * bfhi(ev[k].x);
                m2 += w * bflo(ev[k].y); m3 += w * bfhi(ev[k].y);
                m4 += w * bflo(ev[k].z); m5 += w * bfhi(ev[k].z);
                m6 += w * bflo(ev[k].w); m7 += w * bfhi(ev[k].w);
            }
            const float scl = (len > 0) ? (1.f / (float)len) : 0.f;
            a5[0] = (short)f2bf(m0 * scl); a5[1] = (short)f2bf(m1 * scl);
            a5[2] = (short)f2bf(m2 * scl); a5[3] = (short)f2bf(m3 * scl);
            a5[4] = (short)f2bf(m4 * scl); a5[5] = (short)f2bf(m5 * scl);
            a5[6] = (short)f2bf(m6 * scl); a5[7] = (short)f2bf(m7 * scl);
        }

        // ---------- MFMA in 2 passes of 4 col-tiles (acc = 64 regs) ----------
        float part[16];
        #pragma unroll
        for (int r = 0; r < 16; ++r) part[r] = 0.f;

        #pragma unroll
        for (int p = 0; p < 2; ++p) {
            f32x16 acc[4];
            #pragma unroll
            for (int j = 0; j < 4; ++j)
                #pragma unroll
                for (int r = 0; r < 16; ++r) acc[j][r] = b1r[4 * p + j];   // b1 folded in

            #pragma unroll
            for (int kk = 0; kk < 6; ++kk) {
                const short8 av = (kk == 0) ? a0 : (kk == 1) ? a1 : (kk == 2) ? a2
                               : (kk == 3) ? a3 : (kk == 4) ? a4 : a5;
                const int s = kk * 2 + hi;
                #pragma unroll
                for (int j = 0; j < 4; ++j) {
                    const int col = (4 * p + j) * 32 + l31;
                    short8 bv = *(const short8*)(&w1t[col * 104 + s * 8]);
                    acc[j] = __builtin_amdgcn_mfma_f32_32x32x16_bf16(av, bv, acc[j], 0, 0, 0);
                }
            }

            #pragma unroll
            for (int j = 0; j < 4; ++j) {
                #pragma unroll
                for (int r = 0; r < 16; ++r) {
                    float h = acc[j][r];
                    h = h > 0.f ? h : 0.f;
                    part[r] += h * w2r[4 * p + j];
                }
            }
        }

        // ---------- split-register butterfly reduce over 32 lanes ----------
        const int b_ = (l31 >> 4) & 1, c_ = (l31 >> 3) & 1,
                  d_ = (l31 >> 2) & 1, e_ = (l31 >> 1) & 1;
        float p1[8], p2[4], p3[2], p4, p5;
        #pragma unroll
        for (int i = 0; i < 8; ++i) {
            float keep = b_ ? part[8 + i] : part[i];
            float send = b_ ? part[i]     : part[8 + i];
            p1[i] = keep + __shfl_xor(send, 16, 64);
        }
        #pragma unroll
        for (int i = 0; i < 4; ++i) {
            float keep = c_ ? p1[4 + i] : p1[i];
            float send = c_ ? p1[i]     : p1[4 + i];
            p2[i] = keep + __shfl_xor(send, 8, 64);
        }
        #pragma unroll
        for (int i = 0; i < 2; ++i) {
            float keep = d_ ? p2[2 + i] : p2[i];
            float send = d_ ? p2[i]     : p2[2 + i];
            p3[i] = keep + __shfl_xor(send, 4, 64);
        }
        {
            float keep = e_ ? p3[1] : p3[0];
            float send = e_ ? p3[0] : p3[1];
            p4 = keep + __shfl_xor(send, 2, 64);
        }
        p5 = p4 + __shfl_xor(p4, 1, 64);
        // lane l31 now holds the full sum for r = l31>>1 (row = (r&3)+8*(r>>2)+4*hi)

        // ---------- single coalesced store (one 128 B line per wave) ----------
        if (!(lane & 1)) {
            const int r = l31 >> 1;
            out[tile * 128 + wv * 32 + (r & 3) + 8 * (r >> 2) + 4 * hi] = p5 + b2v;
        }
    }
#undef LOADIDX
}

extern "C" void kernel_launch(void* const* d_in, const int* in_sizes, int n_in,
                              void* d_out, int out_size, void* d_ws, size_t ws_size,
                              hipStream_t stream) {
    const int*   gidx = (const int*)d_in[0];
    const int*   cidx = (const int*)d_in[1];
    const int*   pidx = (const int*)d_in[2];
    const int*   plen = (const int*)d_in[3];
    const int*   aidx = (const int*)d_in[4];
    const int*   alen = (const int*)d_in[5];
    const float* gt   = (const float*)d_in[6];
    const float* ct   = (const float*)d_in[7];
    const float* W1   = (const float*)d_in[8];
    const float* b1   = (const float*)d_in[9];
    const float* W2   = (const float*)d_in[10];
    const float* b2   = (const float*)d_in[11];
    float* out = (float*)d_out;
    unsigned short* ws = (unsigned short*)d_ws;

    const int B = in_sizes[0] / 5;          // 1048576
    prep_kernel<<<96, 256, 0, stream>>>(gt, ct, W1, ws);

    const int tilesTotal = B / 128;         // rows handled per block-tile = 128
    int tpb = 8;
    while (tpb > 1 && (tilesTotal % tpb)) tpb >>= 1;
    const int blocks = tilesTotal / tpb;
    wordle_kernel<<<blocks, 256, 0, stream>>>(gidx, cidx, pidx, plen, aidx, alen,
                                              b1, W2, b2, ws, out, tpb);
}

// Round 4
// 596.536 us; speedup vs baseline: 1.0624x; 1.0624x over previous
//
#include <hip/hip_runtime.h>

typedef __attribute__((ext_vector_type(8))) short short8;
typedef __attribute__((ext_vector_type(16))) float f32x16;

// d_ws layout (ushort elements):
#define WS_GT   0        // 26*8 = 208 bf16
#define WS_CT   256      // 27*8 = 216 bf16
#define WS_W1T  512      // 256 cols * 13 slots * 8 bf16 = 26624 ushorts (52 KB)

__device__ __forceinline__ unsigned short f2bf(float f) {
    unsigned int u = __float_as_uint(f);
    u = (u + 0x7fffu + ((u >> 16) & 1u)) >> 16;   // RNE
    return (unsigned short)u;
}
__device__ __forceinline__ float bflo(unsigned int w) { return __uint_as_float(w << 16); }
__device__ __forceinline__ float bfhi(unsigned int w) { return __uint_as_float(w & 0xffff0000u); }

// W1 stored transposed [col][13 slots of 8]; 208 B col stride (odd multiple of
// 16 B -> ds_read_b128 conflict-free without swizzle, verified: 0 conflicts).
__global__ __launch_bounds__(256) void prep_kernel(
    const float* __restrict__ gt, const float* __restrict__ ct,
    const float* __restrict__ W1, unsigned short* __restrict__ ws)
{
    int tid = blockIdx.x * 256 + threadIdx.x;
    if (tid < 208) ws[WS_GT + tid] = f2bf(gt[tid]);
    if (tid < 216) ws[WS_CT + tid] = f2bf(ct[tid]);
    if (tid < 24576) {
        int kl  = tid >> 8;     // logical k 0..95
        int col = tid & 255;    // hidden col 0..255
        int chunk = kl >> 3, j = kl & 7;
        int hi, kk;
        if (chunk < 5)        { hi = 0; kk = chunk; }      // guess letters -> half 0
        else if (chunk < 10)  { hi = 1; kk = chunk - 5; }  // constraint letters -> half 1
        else if (chunk == 10) { hi = 0; kk = 5; }          // presence mean -> half 0
        else                  { hi = 1; kk = 5; }          // absent mean  -> half 1
        int s = kk * 2 + hi;                                // physical k-slot 0..11
        ws[WS_W1T + col * 104 + s * 8 + j] = f2bf(W1[kl * 256 + col]);
    }
}

#define LOADIDX(T) do {                                                     \
        const int r_ = (blockIdx.x * tilesPerBlock + (T)) * 128 + wv * 32 + l31; \
        const int* ip_ = (hi ? cidx : gidx) + r_ * 5;                       \
        ip0 = ip_[0]; ip1 = ip_[1]; ip2 = ip_[2]; ip3 = ip_[3]; ip4 = ip_[4]; \
        const int* si_ = (hi ? aidx : pidx) + r_ * 10;                      \
        s0 = si_[0]; s1 = si_[1]; s2 = si_[2]; s3 = si_[3]; s4 = si_[4];    \
        s5 = si_[5]; s6 = si_[6]; s7 = si_[7]; s8 = si_[8]; s9 = si_[9];    \
        lenv = (hi ? alen : plen)[r_];                                      \
    } while (0)

// Issue all 15 table gathers for the tile whose indices are in ip*/s* regs.
#define GATHER(S) do {                                                      \
        a0##S = *(const short8*)(tb + ip0 * 8);                             \
        a1##S = *(const short8*)(tb + ip1 * 8);                             \
        a2##S = *(const short8*)(tb + ip2 * 8);                             \
        a3##S = *(const short8*)(tb + ip3 * 8);                             \
        a4##S = *(const short8*)(tb + ip4 * 8);                             \
        e0##S = *(const uint4*)(gt + s0 * 8);                               \
        e1##S = *(const uint4*)(gt + s1 * 8);                               \
        e2##S = *(const uint4*)(gt + s2 * 8);                               \
        e3##S = *(const uint4*)(gt + s3 * 8);                               \
        e4##S = *(const uint4*)(gt + s4 * 8);                               \
        e5##S = *(const uint4*)(gt + s5 * 8);                               \
        e6##S = *(const uint4*)(gt + s6 * 8);                               \
        e7##S = *(const uint4*)(gt + s7 * 8);                               \
        e8##S = *(const uint4*)(gt + s8 * 8);                               \
        e9##S = *(const uint4*)(gt + s9 * 8);                               \
        len##S = lenv;                                                      \
    } while (0)

#define MACC(K, EV) { const float w_ = ((K) < len_) ? 1.f : 0.f;            \
        m0 += w_ * bflo((EV).x); m1 += w_ * bfhi((EV).x);                   \
        m2 += w_ * bflo((EV).y); m3 += w_ * bfhi((EV).y);                   \
        m4 += w_ * bflo((EV).z); m5 += w_ * bfhi((EV).z);                   \
        m6 += w_ * bflo((EV).w); m7 += w_ * bfhi((EV).w); }

#define TILE(T, C, N) do {                                                  \
    const int tile_ = blockIdx.x * tilesPerBlock + (T);                     \
    /* prefetch: next tile's gathers, then tile-after-next's indices */     \
    if ((T) + 1 < tilesPerBlock) { GATHER(N); }                             \
    if ((T) + 2 < tilesPerBlock) { LOADIDX((T) + 2); }                      \
    /* masked mean from set C */                                            \
    short8 a5;                                                              \
    {                                                                       \
        const int len_ = len##C;                                            \
        float m0=0.f,m1=0.f,m2=0.f,m3=0.f,m4=0.f,m5=0.f,m6=0.f,m7=0.f;     \
        MACC(0, e0##C) MACC(1, e1##C) MACC(2, e2##C) MACC(3, e3##C)         \
        MACC(4, e4##C) MACC(5, e5##C) MACC(6, e6##C) MACC(7, e7##C)         \
        MACC(8, e8##C) MACC(9, e9##C)                                       \
        const float scl = (len_ > 0) ? (1.f / (float)len_) : 0.f;           \
        a5[0] = (short)f2bf(m0 * scl); a5[1] = (short)f2bf(m1 * scl);       \
        a5[2] = (short)f2bf(m2 * scl); a5[3] = (short)f2bf(m3 * scl);       \
        a5[4] = (short)f2bf(m4 * scl); a5[5] = (short)f2bf(m5 * scl);       \
        a5[6] = (short)f2bf(m6 * scl); a5[7] = (short)f2bf(m7 * scl);       \
    }                                                                       \
    /* MFMA in 2 passes of 4 col-tiles (acc = 64 regs) */                   \
    float part[16];                                                         \
    _Pragma("unroll") for (int r = 0; r < 16; ++r) part[r] = 0.f;           \
    _Pragma("unroll") for (int p = 0; p < 2; ++p) {                         \
        f32x16 acc[4];                                                      \
        _Pragma("unroll") for (int j = 0; j < 4; ++j)                       \
            _Pragma("unroll") for (int r = 0; r < 16; ++r)                  \
                acc[j][r] = b1r[4 * p + j];                                 \
        _Pragma("unroll") for (int kk = 0; kk < 6; ++kk) {                  \
            const short8 av = (kk == 0) ? a0##C : (kk == 1) ? a1##C         \
                            : (kk == 2) ? a2##C : (kk == 3) ? a3##C         \
                            : (kk == 4) ? a4##C : a5;                       \
            const int s_ = kk * 2 + hi;                                     \
            _Pragma("unroll") for (int j = 0; j < 4; ++j) {                 \
                const int col = (4 * p + j) * 32 + l31;                     \
                short8 bv = *(const short8*)(&w1t[col * 104 + s_ * 8]);     \
                acc[j] = __builtin_amdgcn_mfma_f32_32x32x16_bf16(av, bv, acc[j], 0, 0, 0); \
            }                                                               \
        }                                                                   \
        _Pragma("unroll") for (int j = 0; j < 4; ++j)                       \
            _Pragma("unroll") for (int r = 0; r < 16; ++r) {                \
                float h = acc[j][r]; h = h > 0.f ? h : 0.f;                 \
                part[r] += h * w2r[4 * p + j];                              \
            }                                                               \
    }                                                                       \
    /* split-register butterfly reduce over 32 lanes */                     \
    {                                                                       \
        const int b_ = (l31 >> 4) & 1, c_ = (l31 >> 3) & 1,                 \
                  d_ = (l31 >> 2) & 1, e_ = (l31 >> 1) & 1;                 \
        float p1[8], p2[4], p3[2], p4, p5;                                  \
        _Pragma("unroll") for (int i = 0; i < 8; ++i) {                     \
            float keep = b_ ? part[8 + i] : part[i];                        \
            float send = b_ ? part[i]     : part[8 + i];                    \
            p1[i] = keep + __shfl_xor(send, 16, 64);                        \
        }                                                                   \
        _Pragma("unroll") for (int i = 0; i < 4; ++i) {                     \
            float keep = c_ ? p1[4 + i] : p1[i];                            \
            float send = c_ ? p1[i]     : p1[4 + i];                        \
            p2[i] = keep + __shfl_xor(send, 8, 64);                         \
        }                                                                   \
        _Pragma("unroll") for (int i = 0; i < 2; ++i) {                     \
            float keep = d_ ? p2[2 + i] : p2[i];                            \
            float send = d_ ? p2[i]     : p2[2 + i];                        \
            p3[i] = keep + __shfl_xor(send, 4, 64);                         \
        }                                                                   \
        {                                                                   \
            float keep = e_ ? p3[1] : p3[0];                                \
            float send = e_ ? p3[0] : p3[1];                                \
            p4 = keep + __shfl_xor(send, 2, 64);                            \
        }                                                                   \
        p5 = p4 + __shfl_xor(p4, 1, 64);                                    \
        if (!(lane & 1)) {                                                  \
            const int r = l31 >> 1;                                         \
            out[tile_ * 128 + wv * 32 + (r & 3) + 8 * (r >> 2) + 4 * hi] = p5 + b2v; \
        }                                                                   \
    }                                                                       \
} while (0)

__global__ __launch_bounds__(256, 2) void wordle_kernel(
    const int* __restrict__ gidx, const int* __restrict__ cidx,
    const int* __restrict__ pidx, const int* __restrict__ plen,
    const int* __restrict__ aidx, const int* __restrict__ alen,
    const float* __restrict__ b1, const float* __restrict__ W2,
    const float* __restrict__ b2, const unsigned short* __restrict__ ws,
    float* __restrict__ out, int tilesPerBlock)
{
    __shared__ unsigned short w1t[26624];   // 52 KB

    // Stage W1T (linear coalesced copy; layout pre-applied in d_ws)
    {
        const uint4* src = (const uint4*)(ws + WS_W1T);
        uint4* dst = (uint4*)w1t;
        int tid = threadIdx.x;
        #pragma unroll
        for (int i = 0; i < 13; ++i) dst[tid + i * 256] = src[tid + i * 256];
    }
    __syncthreads();

    const int lane = threadIdx.x & 63;
    const int wv   = threadIdx.x >> 6;
    const int l31  = lane & 31;
    const int hi   = lane >> 5;
    const unsigned short* gt = ws + WS_GT;
    const unsigned short* ct = ws + WS_CT;
    const unsigned short* tb = hi ? ct : gt;
    const float b2v = b2[0];

    // Hoisted epilogue weights (8 col-tiles of 32)
    float w2r[8], b1r[8];
    #pragma unroll
    for (int nt = 0; nt < 8; ++nt) {
        w2r[nt] = W2[nt * 32 + l31];
        b1r[nt] = b1[nt * 32 + l31];
    }

    // index regs (always hold the next tile whose gathers are not yet issued)
    int ip0, ip1, ip2, ip3, ip4;
    int s0, s1, s2, s3, s4, s5, s6, s7, s8, s9;
    int lenv;

    // ping-pong gather register sets
    short8 a0P, a1P, a2P, a3P, a4P; uint4 e0P, e1P, e2P, e3P, e4P, e5P, e6P, e7P, e8P, e9P; int lenP;
    short8 a0Q, a1Q, a2Q, a3Q, a4Q; uint4 e0Q, e1Q, e2Q, e3Q, e4Q, e5Q, e6Q, e7Q, e8Q, e9Q; int lenQ;

    LOADIDX(0);
    GATHER(P);                          // tile 0 gathers in flight
    if (tilesPerBlock > 1) LOADIDX(1);  // idx for tile 1

    int t = 0;
    for (; t + 1 < tilesPerBlock; t += 2) {
        TILE(t, P, Q);
        TILE(t + 1, Q, P);
    }
    if (t < tilesPerBlock) TILE(t, P, Q);
}

extern "C" void kernel_launch(void* const* d_in, const int* in_sizes, int n_in,
                              void* d_out, int out_size, void* d_ws, size_t ws_size,
                              hipStream_t stream) {
    const int*   gidx = (const int*)d_in[0];
    const int*   cidx = (const int*)d_in[1];
    const int*   pidx = (const int*)d_in[2];
    const int*   plen = (const int*)d_in[3];
    const int*   aidx = (const int*)d_in[4];
    const int*   alen = (const int*)d_in[5];
    const float* gt   = (const float*)d_in[6];
    const float* ct   = (const float*)d_in[7];
    const float* W1   = (const float*)d_in[8];
    const float* b1   = (const float*)d_in[9];
    const float* W2   = (const float*)d_in[10];
    const float* b2   = (const float*)d_in[11];
    float* out = (float*)d_out;
    unsigned short* ws = (unsigned short*)d_ws;

    const int B = in_sizes[0] / 5;          // 1048576
    prep_kernel<<<96, 256, 0, stream>>>(gt, ct, W1, ws);

    const int tilesTotal = B / 128;         // 8192 block-tiles of 128 rows
    int tpb = 16;                           // 512 persistent blocks = 2/CU
    while (tpb > 1 && (tilesTotal % tpb)) tpb >>= 1;
    const int blocks = tilesTotal / tpb;
    wordle_kernel<<<blocks, 256, 0, stream>>>(gidx, cidx, pidx, plen, aidx, alen,
                                              b1, W2, b2, ws, out, tpb);
}

// Round 5
// 436.282 us; speedup vs baseline: 1.4526x; 1.3673x over previous
//
#include <hip/hip_runtime.h>

typedef __attribute__((ext_vector_type(8))) short short8;
typedef __attribute__((ext_vector_type(16))) float f32x16;

// d_ws layout (ushort elements):
#define WS_GT   0        // 26*8 = 208 bf16
#define WS_CT   256      // 27*8 = 216 bf16
#define WS_W1T  512      // 256 cols * 13 slots * 8 bf16 = 26624 ushorts (52 KB)

__device__ __forceinline__ unsigned short f2bf(float f) {
    unsigned int u = __float_as_uint(f);
    u = (u + 0x7fffu + ((u >> 16) & 1u)) >> 16;   // RNE
    return (unsigned short)u;
}
__device__ __forceinline__ float bflo(unsigned int w) { return __uint_as_float(w << 16); }
__device__ __forceinline__ float bfhi(unsigned int w) { return __uint_as_float(w & 0xffff0000u); }

// W1 stored transposed [col][13 slots of 8]; 208 B col stride (odd multiple of
// 16 B -> ds_read_b128 conflict-free without swizzle, verified: 0 conflicts).
__global__ __launch_bounds__(256) void prep_kernel(
    const float* __restrict__ gt, const float* __restrict__ ct,
    const float* __restrict__ W1, unsigned short* __restrict__ ws)
{
    int tid = blockIdx.x * 256 + threadIdx.x;
    if (tid < 208) ws[WS_GT + tid] = f2bf(gt[tid]);
    if (tid < 216) ws[WS_CT + tid] = f2bf(ct[tid]);
    if (tid < 24576) {
        int kl  = tid >> 8;     // logical k 0..95
        int col = tid & 255;    // hidden col 0..255
        int chunk = kl >> 3, j = kl & 7;
        int hi, kk;
        if (chunk < 5)        { hi = 0; kk = chunk; }      // guess letters -> half 0
        else if (chunk < 10)  { hi = 1; kk = chunk - 5; }  // constraint letters -> half 1
        else if (chunk == 10) { hi = 0; kk = 5; }          // presence mean -> half 0
        else                  { hi = 1; kk = 5; }          // absent mean  -> half 1
        int s = kk * 2 + hi;                                // physical k-slot 0..11
        ws[WS_W1T + col * 104 + s * 8 + j] = f2bf(W1[kl * 256 + col]);
    }
}

#define LOADIDX(T) do {                                                     \
        const int r_ = (blockIdx.x * tilesPerBlock + (T)) * 128 + wv * 32 + l31; \
        const int* ip_ = (hi ? cidx : gidx) + r_ * 5;                       \
        ip0 = ip_[0]; ip1 = ip_[1]; ip2 = ip_[2]; ip3 = ip_[3]; ip4 = ip_[4]; \
        const int* si_ = (hi ? aidx : pidx) + r_ * 10;                      \
        s0 = si_[0]; s1 = si_[1]; s2 = si_[2]; s3 = si_[3]; s4 = si_[4];    \
        s5 = si_[5]; s6 = si_[6]; s7 = si_[7]; s8 = si_[8]; s9 = si_[9];    \
        lenv = (hi ? alen : plen)[r_];                                      \
    } while (0)

// Issue the 5 letter gathers into ping-pong set S (20 VGPRs).
#define GATHER_A(S) do {                                                    \
        a0##S = *(const short8*)(tb + ip0 * 8);                             \
        a1##S = *(const short8*)(tb + ip1 * 8);                             \
        a2##S = *(const short8*)(tb + ip2 * 8);                             \
        a3##S = *(const short8*)(tb + ip3 * 8);                             \
        a4##S = *(const short8*)(tb + ip4 * 8);                             \
    } while (0)

#define MACC(K, EV) { const float w_ = ((K) < len_) ? 1.f : 0.f;            \
        m0 += w_ * bflo((EV).x); m1 += w_ * bfhi((EV).x);                   \
        m2 += w_ * bflo((EV).y); m3 += w_ * bfhi((EV).y);                   \
        m4 += w_ * bflo((EV).z); m5 += w_ * bfhi((EV).z);                   \
        m6 += w_ * bflo((EV).w); m7 += w_ * bfhi((EV).w); }

// One 128-row tile. C = current a-set, N = next a-set (prefetched at end).
#define TILE(T, C, N) do {                                                  \
    const int tile_ = blockIdx.x * tilesPerBlock + (T);                     \
    /* issue set-mean gathers for THIS tile (idx regs hold tile T) */       \
    const int len_ = lenv;                                                  \
    uint4 e0 = *(const uint4*)(gt + s0 * 8);                                \
    uint4 e1 = *(const uint4*)(gt + s1 * 8);                                \
    uint4 e2 = *(const uint4*)(gt + s2 * 8);                                \
    uint4 e3 = *(const uint4*)(gt + s3 * 8);                                \
    uint4 e4 = *(const uint4*)(gt + s4 * 8);                                \
    uint4 e5 = *(const uint4*)(gt + s5 * 8);                                \
    uint4 e6 = *(const uint4*)(gt + s6 * 8);                                \
    uint4 e7 = *(const uint4*)(gt + s7 * 8);                                \
    uint4 e8 = *(const uint4*)(gt + s8 * 8);                                \
    uint4 e9 = *(const uint4*)(gt + s9 * 8);                                \
    /* prefetch next tile's indices (hides under MFMA) */                   \
    if ((T) + 1 < tilesPerBlock) LOADIDX((T) + 1);                          \
    float part[16];                                                         \
    _Pragma("unroll") for (int r = 0; r < 16; ++r) part[r] = 0.f;           \
    /* ---- pass 0, kk=0..4: covers e-gather latency with MFMAs ---- */     \
    f32x16 acc[4];                                                          \
    _Pragma("unroll") for (int j = 0; j < 4; ++j)                           \
        _Pragma("unroll") for (int r = 0; r < 16; ++r) acc[j][r] = b1r[j];  \
    _Pragma("unroll") for (int kk = 0; kk < 5; ++kk) {                      \
        const short8 av = (kk == 0) ? a0##C : (kk == 1) ? a1##C             \
                        : (kk == 2) ? a2##C : (kk == 3) ? a3##C : a4##C;    \
        const int s_ = kk * 2 + hi;                                         \
        _Pragma("unroll") for (int j = 0; j < 4; ++j) {                     \
            short8 bv = *(const short8*)(&w1t[(j * 32 + l31) * 104 + s_ * 8]); \
            acc[j] = __builtin_amdgcn_mfma_f32_32x32x16_bf16(av, bv, acc[j], 0, 0, 0); \
        }                                                                   \
    }                                                                       \
    /* ---- masked mean -> a5 (e-loads have had ~20 MFMAs to land) ---- */  \
    short8 a5;                                                              \
    {                                                                       \
        float m0=0.f,m1=0.f,m2=0.f,m3=0.f,m4=0.f,m5=0.f,m6=0.f,m7=0.f;     \
        MACC(0, e0) MACC(1, e1) MACC(2, e2) MACC(3, e3) MACC(4, e4)         \
        MACC(5, e5) MACC(6, e6) MACC(7, e7) MACC(8, e8) MACC(9, e9)         \
        const float scl = (len_ > 0) ? (1.f / (float)len_) : 0.f;           \
        a5[0] = (short)f2bf(m0 * scl); a5[1] = (short)f2bf(m1 * scl);       \
        a5[2] = (short)f2bf(m2 * scl); a5[3] = (short)f2bf(m3 * scl);       \
        a5[4] = (short)f2bf(m4 * scl); a5[5] = (short)f2bf(m5 * scl);       \
        a5[6] = (short)f2bf(m6 * scl); a5[7] = (short)f2bf(m7 * scl);       \
    }                                                                       \
    _Pragma("unroll") for (int j = 0; j < 4; ++j) {                         \
        short8 bv = *(const short8*)(&w1t[(j * 32 + l31) * 104 + (10 + hi) * 8]); \
        acc[j] = __builtin_amdgcn_mfma_f32_32x32x16_bf16(a5, bv, acc[j], 0, 0, 0); \
    }                                                                       \
    _Pragma("unroll") for (int j = 0; j < 4; ++j)                           \
        _Pragma("unroll") for (int r = 0; r < 16; ++r) {                    \
            float h = acc[j][r]; h = h > 0.f ? h : 0.f;                     \
            part[r] += h * w2r[j];                                          \
        }                                                                   \
    /* ---- pass 1: cols 128..255, all 6 k-slices ---- */                   \
    _Pragma("unroll") for (int j = 0; j < 4; ++j)                           \
        _Pragma("unroll") for (int r = 0; r < 16; ++r) acc[j][r] = b1r[4 + j]; \
    _Pragma("unroll") for (int kk = 0; kk < 6; ++kk) {                      \
        const short8 av = (kk == 0) ? a0##C : (kk == 1) ? a1##C             \
                        : (kk == 2) ? a2##C : (kk == 3) ? a3##C             \
                        : (kk == 4) ? a4##C : a5;                           \
        const int s_ = kk * 2 + hi;                                         \
        _Pragma("unroll") for (int j = 0; j < 4; ++j) {                     \
            short8 bv = *(const short8*)(&w1t[((4 + j) * 32 + l31) * 104 + s_ * 8]); \
            acc[j] = __builtin_amdgcn_mfma_f32_32x32x16_bf16(av, bv, acc[j], 0, 0, 0); \
        }                                                                   \
    }                                                                       \
    _Pragma("unroll") for (int j = 0; j < 4; ++j)                           \
        _Pragma("unroll") for (int r = 0; r < 16; ++r) {                    \
            float h = acc[j][r]; h = h > 0.f ? h : 0.f;                     \
            part[r] += h * w2r[4 + j];                                      \
        }                                                                   \
    /* ---- prefetch next tile's letter gathers (hides under reduce) ---- */\
    if ((T) + 1 < tilesPerBlock) GATHER_A(N);                               \
    /* ---- split-register butterfly reduce over 32 lanes ---- */           \
    {                                                                       \
        const int b_ = (l31 >> 4) & 1, c_ = (l31 >> 3) & 1,                 \
                  d_ = (l31 >> 2) & 1, e_ = (l31 >> 1) & 1;                 \
        float p1[8], p2[4], p3[2], p4, p5;                                  \
        _Pragma("unroll") for (int i = 0; i < 8; ++i) {                     \
            float keep = b_ ? part[8 + i] : part[i];                        \
            float send = b_ ? part[i]     : part[8 + i];                    \
            p1[i] = keep + __shfl_xor(send, 16, 64);                        \
        }                                                                   \
        _Pragma("unroll") for (int i = 0; i < 4; ++i) {                     \
            float keep = c_ ? p1[4 + i] : p1[i];                            \
            float send = c_ ? p1[i]     : p1[4 + i];                        \
            p2[i] = keep + __shfl_xor(send, 8, 64);                         \
        }                                                                   \
        _Pragma("unroll") for (int i = 0; i < 2; ++i) {                     \
            float keep = d_ ? p2[2 + i] : p2[i];                            \
            float send = d_ ? p2[i]     : p2[2 + i];                        \
            p3[i] = keep + __shfl_xor(send, 4, 64);                         \
        }                                                                   \
        {                                                                   \
            float keep = e_ ? p3[1] : p3[0];                                \
            float send = e_ ? p3[0] : p3[1];                                \
            p4 = keep + __shfl_xor(send, 2, 64);                            \
        }                                                                   \
        p5 = p4 + __shfl_xor(p4, 1, 64);                                    \
        if (!(lane & 1)) {                                                  \
            const int r = l31 >> 1;                                         \
            out[tile_ * 128 + wv * 32 + (r & 3) + 8 * (r >> 2) + 4 * hi] = p5 + b2v; \
        }                                                                   \
    }                                                                       \
} while (0)

__global__ __launch_bounds__(256, 2) void wordle_kernel(
    const int* __restrict__ gidx, const int* __restrict__ cidx,
    const int* __restrict__ pidx, const int* __restrict__ plen,
    const int* __restrict__ aidx, const int* __restrict__ alen,
    const float* __restrict__ b1, const float* __restrict__ W2,
    const float* __restrict__ b2, const unsigned short* __restrict__ ws,
    float* __restrict__ out, int tilesPerBlock)
{
    __shared__ unsigned short w1t[26624];   // 52 KB

    // Stage W1T (linear coalesced copy; layout pre-applied in d_ws)
    {
        const uint4* src = (const uint4*)(ws + WS_W1T);
        uint4* dst = (uint4*)w1t;
        int tid = threadIdx.x;
        #pragma unroll
        for (int i = 0; i < 13; ++i) dst[tid + i * 256] = src[tid + i * 256];
    }
    __syncthreads();

    const int lane = threadIdx.x & 63;
    const int wv   = threadIdx.x >> 6;
    const int l31  = lane & 31;
    const int hi   = lane >> 5;
    const unsigned short* gt = ws + WS_GT;
    const unsigned short* ct = ws + WS_CT;
    const unsigned short* tb = hi ? ct : gt;
    const float b2v = b2[0];

    // Hoisted epilogue weights (8 col-tiles of 32)
    float w2r[8], b1r[8];
    #pragma unroll
    for (int nt = 0; nt < 8; ++nt) {
        w2r[nt] = W2[nt * 32 + l31];
        b1r[nt] = b1[nt * 32 + l31];
    }

    // index regs (hold the tile whose a-gathers are NOT yet issued)
    int ip0, ip1, ip2, ip3, ip4;
    int s0, s1, s2, s3, s4, s5, s6, s7, s8, s9;
    int lenv;

    // ping-pong letter-gather sets (20 VGPRs each)
    short8 a0P, a1P, a2P, a3P, a4P;
    short8 a0Q, a1Q, a2Q, a3Q, a4Q;

    LOADIDX(0);
    GATHER_A(P);                         // tile 0 letter gathers in flight

    int t = 0;
    for (; t + 1 < tilesPerBlock; t += 2) {
        TILE(t, P, Q);
        TILE(t + 1, Q, P);
    }
    if (t < tilesPerBlock) TILE(t, P, Q);
}

extern "C" void kernel_launch(void* const* d_in, const int* in_sizes, int n_in,
                              void* d_out, int out_size, void* d_ws, size_t ws_size,
                              hipStream_t stream) {
    const int*   gidx = (const int*)d_in[0];
    const int*   cidx = (const int*)d_in[1];
    const int*   pidx = (const int*)d_in[2];
    const int*   plen = (const int*)d_in[3];
    const int*   aidx = (const int*)d_in[4];
    const int*   alen = (const int*)d_in[5];
    const float* gt   = (const float*)d_in[6];
    const float* ct   = (const float*)d_in[7];
    const float* W1   = (const float*)d_in[8];
    const float* b1   = (const float*)d_in[9];
    const float* W2   = (const float*)d_in[10];
    const float* b2   = (const float*)d_in[11];
    float* out = (float*)d_out;
    unsigned short* ws = (unsigned short*)d_ws;

    const int B = in_sizes[0] / 5;          // 1048576
    prep_kernel<<<96, 256, 0, stream>>>(gt, ct, W1, ws);

    const int tilesTotal = B / 128;         // 8192 block-tiles of 128 rows
    int tpb = 16;                           // 512 persistent blocks = 2/CU
    while (tpb > 1 && (tilesTotal % tpb)) tpb >>= 1;
    const int blocks = tilesTotal / tpb;
    wordle_kernel<<<blocks, 256, 0, stream>>>(gidx, cidx, pidx, plen, aidx, alen,
                                              b1, W2, b2, ws, out, tpb);
}

// Round 6
// 371.600 us; speedup vs baseline: 1.7054x; 1.1741x over previous
//
#include <hip/hip_runtime.h>

typedef __attribute__((ext_vector_type(8))) short short8;
typedef __attribute__((ext_vector_type(16))) float f32x16;

// d_ws layout (ushort elements):
#define WS_GT   0        // 26*8 = 208 bf16
#define WS_CT   256      // 27*8 = 216 bf16
#define WS_W1T  512      // 256 cols * 13 slots * 8 bf16 = 26624 ushorts (52 KB)

__device__ __forceinline__ unsigned short f2bf(float f) {
    unsigned int u = __float_as_uint(f);
    u = (u + 0x7fffu + ((u >> 16) & 1u)) >> 16;   // RNE
    return (unsigned short)u;
}
__device__ __forceinline__ float bflo(unsigned int w) { return __uint_as_float(w << 16); }
__device__ __forceinline__ float bfhi(unsigned int w) { return __uint_as_float(w & 0xffff0000u); }

// W1 stored transposed [col][13 slots of 8]; 208 B col stride (odd multiple of
// 16 B -> ds_read_b128 conflict-free without swizzle; verified: 0 conflicts).
__global__ __launch_bounds__(256) void prep_kernel(
    const float* __restrict__ gt, const float* __restrict__ ct,
    const float* __restrict__ W1, unsigned short* __restrict__ ws)
{
    int tid = blockIdx.x * 256 + threadIdx.x;
    if (tid < 208) ws[WS_GT + tid] = f2bf(gt[tid]);
    if (tid < 216) ws[WS_CT + tid] = f2bf(ct[tid]);
    if (tid < 24576) {
        int kl  = tid >> 8;     // logical k 0..95
        int col = tid & 255;    // hidden col 0..255
        int chunk = kl >> 3, j = kl & 7;
        int hi, kk;
        if (chunk < 5)        { hi = 0; kk = chunk; }      // guess letters -> half 0
        else if (chunk < 10)  { hi = 1; kk = chunk - 5; }  // constraint letters -> half 1
        else if (chunk == 10) { hi = 0; kk = 5; }          // presence mean -> half 0
        else                  { hi = 1; kk = 5; }          // absent mean  -> half 1
        int s = kk * 2 + hi;                                // physical k-slot 0..11
        ws[WS_W1T + col * 104 + s * 8 + j] = f2bf(W1[kl * 256 + col]);
    }
}

__global__ __launch_bounds__(256, 2) void wordle_kernel(
    const int* __restrict__ gidx, const int* __restrict__ cidx,
    const int* __restrict__ pidx, const int* __restrict__ plen,
    const int* __restrict__ aidx, const int* __restrict__ alen,
    const float* __restrict__ b1, const float* __restrict__ W2,
    const float* __restrict__ b2, const unsigned short* __restrict__ ws,
    float* __restrict__ out, int tilesPerBlock)
{
    __shared__ unsigned short w1t[26624];   // 52 KB

    // Stage W1T (linear coalesced copy; layout pre-applied in d_ws)
    {
        const uint4* src = (const uint4*)(ws + WS_W1T);
        uint4* dst = (uint4*)w1t;
        int tid = threadIdx.x;
        #pragma unroll
        for (int i = 0; i < 13; ++i) dst[tid + i * 256] = src[tid + i * 256];
    }
    __syncthreads();

    const int lane = threadIdx.x & 63;
    const int wv   = threadIdx.x >> 6;
    const int l31  = lane & 31;
    const int hi   = lane >> 5;
    const unsigned short* gt = ws + WS_GT;
    const unsigned short* ct = ws + WS_CT;
    const unsigned short* tb = hi ? ct : gt;
    const float b2v = b2[0];

    // Hoisted epilogue weights (8 col-tiles of 32)
    float w2r[8], b1r[8];
    #pragma unroll
    for (int nt = 0; nt < 8; ++nt) {
        w2r[nt] = W2[nt * 32 + l31];
        b1r[nt] = b1[nt * 32 + l31];
    }

    // Prefetched per-row indices for the CURRENT tile
    int ip0, ip1, ip2, ip3, ip4;
    int s0, s1, s2, s3, s4, s5, s6, s7, s8, s9;
    int lenv;

#define LOADIDX(T) do {                                                     \
        const int r_ = (blockIdx.x * tilesPerBlock + (T)) * 128 + wv * 32 + l31; \
        const int* ip_ = (hi ? cidx : gidx) + r_ * 5;                       \
        ip0 = ip_[0]; ip1 = ip_[1]; ip2 = ip_[2]; ip3 = ip_[3]; ip4 = ip_[4]; \
        const int* si_ = (hi ? aidx : pidx) + r_ * 10;                      \
        s0 = si_[0]; s1 = si_[1]; s2 = si_[2]; s3 = si_[3]; s4 = si_[4];    \
        s5 = si_[5]; s6 = si_[6]; s7 = si_[7]; s8 = si_[8]; s9 = si_[9];    \
        lenv = (hi ? alen : plen)[r_];                                      \
    } while (0)

    LOADIDX(0);

    for (int t = 0; t < tilesPerBlock; ++t) {
        const int tile = blockIdx.x * tilesPerBlock + t;

        // ---------- gather: issue all table loads for this tile ----------
        short8 a0 = *(const short8*)(tb + ip0 * 8);
        short8 a1 = *(const short8*)(tb + ip1 * 8);
        short8 a2 = *(const short8*)(tb + ip2 * 8);
        short8 a3 = *(const short8*)(tb + ip3 * 8);
        short8 a4 = *(const short8*)(tb + ip4 * 8);
        uint4 e0 = *(const uint4*)(gt + s0 * 8);
        uint4 e1 = *(const uint4*)(gt + s1 * 8);
        uint4 e2 = *(const uint4*)(gt + s2 * 8);
        uint4 e3 = *(const uint4*)(gt + s3 * 8);
        uint4 e4 = *(const uint4*)(gt + s4 * 8);
        uint4 e5 = *(const uint4*)(gt + s5 * 8);
        uint4 e6 = *(const uint4*)(gt + s6 * 8);
        uint4 e7 = *(const uint4*)(gt + s7 * 8);
        uint4 e8 = *(const uint4*)(gt + s8 * 8);
        uint4 e9 = *(const uint4*)(gt + s9 * 8);
        const int len = lenv;

        // ---------- prefetch next tile's indices (hides under MFMA) ----------
        if (t + 1 < tilesPerBlock) LOADIDX(t + 1);

        // ---------- masked mean -> a5 ----------
        short8 a5;
        {
            float m0=0.f,m1=0.f,m2=0.f,m3=0.f,m4=0.f,m5=0.f,m6=0.f,m7=0.f;
            uint4 ev[10] = {e0,e1,e2,e3,e4,e5,e6,e7,e8,e9};
            #pragma unroll
            for (int k = 0; k < 10; ++k) {
                float w = (k < len) ? 1.f : 0.f;
                m0 += w * bflo(ev[k].x); m1 += w * bfhi(ev[k].x);
                m2 += w * bflo(ev[k].y); m3 += w * bfhi(ev[k].y);
                m4 += w * bflo(ev[k].z); m5 += w * bfhi(ev[k].z);
                m6 += w * bflo(ev[k].w); m7 += w * bfhi(ev[k].w);
            }
            const float scl = (len > 0) ? (1.f / (float)len) : 0.f;
            a5[0] = (short)f2bf(m0 * scl); a5[1] = (short)f2bf(m1 * scl);
            a5[2] = (short)f2bf(m2 * scl); a5[3] = (short)f2bf(m3 * scl);
            a5[4] = (short)f2bf(m4 * scl); a5[5] = (short)f2bf(m5 * scl);
            a5[6] = (short)f2bf(m6 * scl); a5[7] = (short)f2bf(m7 * scl);
        }

        // ---------- MFMA in 2 passes of 4 col-tiles (acc = 64 regs) ----------
        float part[16];
        #pragma unroll
        for (int r = 0; r < 16; ++r) part[r] = 0.f;

        #pragma unroll
        for (int p = 0; p < 2; ++p) {
            f32x16 acc[4];
            #pragma unroll
            for (int j = 0; j < 4; ++j)
                #pragma unroll
                for (int r = 0; r < 16; ++r) acc[j][r] = b1r[4 * p + j];   // b1 folded in

            #pragma unroll
            for (int kk = 0; kk < 6; ++kk) {
                const short8 av = (kk == 0) ? a0 : (kk == 1) ? a1 : (kk == 2) ? a2
                               : (kk == 3) ? a3 : (kk == 4) ? a4 : a5;
                const int s = kk * 2 + hi;
                #pragma unroll
                for (int j = 0; j < 4; ++j) {
                    const int col = (4 * p + j) * 32 + l31;
                    short8 bv = *(const short8*)(&w1t[col * 104 + s * 8]);
                    acc[j] = __builtin_amdgcn_mfma_f32_32x32x16_bf16(av, bv, acc[j], 0, 0, 0);
                }
            }

            #pragma unroll
            for (int j = 0; j < 4; ++j) {
                #pragma unroll
                for (int r = 0; r < 16; ++r) {
                    float h = acc[j][r];
                    h = h > 0.f ? h : 0.f;
                    part[r] += h * w2r[4 * p + j];
                }
            }
        }

        // ---------- split-register butterfly reduce over 32 lanes ----------
        const int b_ = (l31 >> 4) & 1, c_ = (l31 >> 3) & 1,
                  d_ = (l31 >> 2) & 1, e_ = (l31 >> 1) & 1;
        float p1[8], p2[4], p3[2], p4, p5;
        #pragma unroll
        for (int i = 0; i < 8; ++i) {
            float keep = b_ ? part[8 + i] : part[i];
            float send = b_ ? part[i]     : part[8 + i];
            p1[i] = keep + __shfl_xor(send, 16, 64);
        }
        #pragma unroll
        for (int i = 0; i < 4; ++i) {
            float keep = c_ ? p1[4 + i] : p1[i];
            float send = c_ ? p1[i]     : p1[4 + i];
            p2[i] = keep + __shfl_xor(send, 8, 64);
        }
        #pragma unroll
        for (int i = 0; i < 2; ++i) {
            float keep = d_ ? p2[2 + i] : p2[i];
            float send = d_ ? p2[i]     : p2[2 + i];
            p3[i] = keep + __shfl_xor(send, 4, 64);
        }
        {
            float keep = e_ ? p3[1] : p3[0];
            float send = e_ ? p3[0] : p3[1];
            p4 = keep + __shfl_xor(send, 2, 64);
        }
        p5 = p4 + __shfl_xor(p4, 1, 64);
        // lane l31 holds the full sum for r = l31>>1 (row = (r&3)+8*(r>>2)+4*hi)

        // ---------- single coalesced store (one 128 B line per wave) ----------
        if (!(lane & 1)) {
            const int r = l31 >> 1;
            out[tile * 128 + wv * 32 + (r & 3) + 8 * (r >> 2) + 4 * hi] = p5 + b2v;
        }
    }
#undef LOADIDX
}

extern "C" void kernel_launch(void* const* d_in, const int* in_sizes, int n_in,
                              void* d_out, int out_size, void* d_ws, size_t ws_size,
                              hipStream_t stream) {
    const int*   gidx = (const int*)d_in[0];
    const int*   cidx = (const int*)d_in[1];
    const int*   pidx = (const int*)d_in[2];
    const int*   plen = (const int*)d_in[3];
    const int*   aidx = (const int*)d_in[4];
    const int*   alen = (const int*)d_in[5];
    const float* gt   = (const float*)d_in[6];
    const float* ct   = (const float*)d_in[7];
    const float* W1   = (const float*)d_in[8];
    const float* b1   = (const float*)d_in[9];
    const float* W2   = (const float*)d_in[10];
    const float* b2   = (const float*)d_in[11];
    float* out = (float*)d_out;
    unsigned short* ws = (unsigned short*)d_ws;

    const int B = in_sizes[0] / 5;          // 1048576
    prep_kernel<<<96, 256, 0, stream>>>(gt, ct, W1, ws);

    const int tilesTotal = B / 128;         // 8192 block-tiles of 128 rows
    int tpb = 16;                           // 512 persistent blocks = 2/CU
    while (tpb > 1 && (tilesTotal % tpb)) tpb >>= 1;
    const int blocks = tilesTotal / tpb;
    wordle_kernel<<<blocks, 256, 0, stream>>>(gidx, cidx, pidx, plen, aidx, alen,
                                              b1, W2, b2, ws, out, tpb);
}